// Round 5
// baseline (298.722 us; speedup 1.0000x reference)
//
#include <hip/hip_runtime.h>

#define B_ 512
#define T_ 512
#define F_ 128
#define H_ 32
#define C_ 6

typedef float f32x2 __attribute__((ext_vector_type(2)));

// ---------------------------------------------------------------------------
// Kernel 1: xz[row][c] = x[row,:] @ Wx[:,c] + bias[c],  row = b*T+t  (M=262144)
// Plain [b][t][128] output layout. mask[row] = any(x[row,:] != 0).
// 256 thr, tile 128x128, K in 2 chunks of 64, reg-prefetch double buffer,
// 64 KB LDS (2 blocks/CU), swizzled xl.  (~70 us, ~79% of f32 FMA floor.)
// ---------------------------------------------------------------------------
__global__ __launch_bounds__(256, 2) void k_xz(
    const float* __restrict__ x, const float* __restrict__ W,
    const float* __restrict__ bias, float* __restrict__ xz,
    float* __restrict__ mask)
{
  __shared__ float xl[128 * 64];   // 32 KB, XOR-swizzled rows
  __shared__ float wl[64 * 128];   // 32 KB, plain
  const int tid = threadIdx.x;
  const int m0  = blockIdx.x * 128;
  const int cg  = tid & 15;        // cols cg*4..+3 and 64+cg*4..+3
  const int rg  = tid >> 4;        // rows rg*8..+7

  float4 xpre[8], wpre[8];
  int rowbits = 0;

  auto load_chunk = [&](int ch) {
#pragma unroll
    for (int k = 0; k < 8; ++k) {
      const int u = tid + k * 256, r = u >> 4, q = u & 15;
      xpre[k] = *(const float4*)(x + (size_t)(m0 + r) * 128 + ch * 64 + q * 4);
    }
#pragma unroll
    for (int k = 0; k < 8; ++k) {
      const int u = tid + k * 256, f = u >> 5, q = u & 31;
      wpre[k] = *(const float4*)(W + (size_t)(ch * 64 + f) * 128 + q * 4);
    }
  };
  auto mask_chunk = [&]() {
#pragma unroll
    for (int k = 0; k < 8; ++k) {
      const float4 v = xpre[k];
      int nb = ((v.x != 0.f) || (v.y != 0.f) || (v.z != 0.f) || (v.w != 0.f)) ? 1 : 0;
      nb |= __shfl_xor(nb, 1); nb |= __shfl_xor(nb, 2);
      nb |= __shfl_xor(nb, 4); nb |= __shfl_xor(nb, 8);
      rowbits |= nb << k;
    }
  };
  auto write_chunk = [&]() {
#pragma unroll
    for (int k = 0; k < 8; ++k) {
      const int u = tid + k * 256, r = u >> 4, q = u & 15;
      *(float4*)(xl + r * 64 + ((q * 4) ^ (((r >> 3) & 3) << 2))) = xpre[k];
    }
#pragma unroll
    for (int k = 0; k < 8; ++k) {
      const int u = tid + k * 256, f = u >> 5, q = u & 31;
      *(float4*)(wl + f * 128 + q * 4) = wpre[k];
    }
  };

  float acc[8][8];
#pragma unroll
  for (int r = 0; r < 8; ++r)
#pragma unroll
    for (int u = 0; u < 8; ++u) acc[r][u] = 0.f;

  auto compute = [&]() {
#pragma unroll 2
    for (int fq = 0; fq < 16; ++fq) {
      float4 xv[8];
#pragma unroll
      for (int r = 0; r < 8; ++r)
        xv[r] = *(const float4*)(xl + (rg * 8 + r) * 64 + ((fq * 4) ^ ((rg & 3) << 2)));
#pragma unroll
      for (int ff = 0; ff < 4; ++ff) {
        const float* wr = wl + (fq * 4 + ff) * 128 + cg * 4;
        const float4 wa = *(const float4*)(wr);
        const float4 wb = *(const float4*)(wr + 64);
#pragma unroll
        for (int r = 0; r < 8; ++r) {
          const float xs = (ff == 0) ? xv[r].x : (ff == 1) ? xv[r].y
                         : (ff == 2) ? xv[r].z : xv[r].w;
          acc[r][0] += xs * wa.x;  acc[r][1] += xs * wa.y;
          acc[r][2] += xs * wa.z;  acc[r][3] += xs * wa.w;
          acc[r][4] += xs * wb.x;  acc[r][5] += xs * wb.y;
          acc[r][6] += xs * wb.z;  acc[r][7] += xs * wb.w;
        }
      }
    }
  };

  load_chunk(0);
  mask_chunk();
  write_chunk();
  __syncthreads();
  load_chunk(1);          // in flight during chunk-0 compute
  compute();
  __syncthreads();
  mask_chunk();
  write_chunk();
  __syncthreads();
  compute();

  // epilogue: bias + store (coalesced float4 pairs)
  float bb[8];
#pragma unroll
  for (int u = 0; u < 4; ++u) {
    bb[u]     = bias[cg * 4 + u];
    bb[4 + u] = bias[64 + cg * 4 + u];
  }
#pragma unroll
  for (int r = 0; r < 8; ++r) {
    float* op = xz + (size_t)(m0 + rg * 8 + r) * 128;
    float4 o0 = { acc[r][0] + bb[0], acc[r][1] + bb[1], acc[r][2] + bb[2], acc[r][3] + bb[3] };
    float4 o1 = { acc[r][4] + bb[4], acc[r][5] + bb[5], acc[r][6] + bb[6], acc[r][7] + bb[7] };
    *(float4*)(op + cg * 4)      = o0;
    *(float4*)(op + 64 + cg * 4) = o1;
  }
  if ((tid & 15) == 0) {
#pragma unroll
    for (int k = 0; k < 8; ++k)
      mask[m0 + k * 16 + rg] = (rowbits >> k) & 1 ? 1.f : 0.f;
  }
}

// ---------------------------------------------------------------------------
// Kernel 2: sequential LSTM scan + FC + softmax.  256 blocks x 64 threads.
// Wave = 2 batch rows; lane j owns gate col j of all 4 gates.
// __launch_bounds__(64,1): full VGPR budget so Whr/ring stay in real VGPRs
// (round-4 ran at VGPR_Count=96 -> Whr lived in AGPRs, accvgpr shuffles per
// FMA).  Depth-4 register prefetch ring amortizes ~900-cyc HBM latency.
// ---------------------------------------------------------------------------
__device__ __forceinline__ float sigmf(float xx) {
  return __builtin_amdgcn_rcpf(1.f + __expf(-xx));
}
__device__ __forceinline__ float tanhf_(float xx) {
  return __builtin_amdgcn_rcpf(1.f + __expf(-2.f * xx)) * 2.f - 1.f;
}

__global__ __launch_bounds__(64, 1) void k_lstm(
    const float* __restrict__ xz, const float* __restrict__ mask,
    const float* __restrict__ Wh, const float* __restrict__ Wfc,
    const float* __restrict__ bfc, float* __restrict__ out)
{
  const int lane = threadIdx.x;
  const int half = lane >> 5;
  const int j = lane & 31;
  const int b = blockIdx.x * 2 + half;

  // Wh packed in f-pairs: Whr[q][g] = (Wh[2q][g*32+j], Wh[2q+1][g*32+j])
  f32x2 Whr[16][4];
#pragma unroll
  for (int q = 0; q < 16; ++q)
#pragma unroll
    for (int g = 0; g < 4; ++g) {
      Whr[q][g][0] = Wh[(2 * q)     * 128 + g * 32 + j];
      Whr[q][g][1] = Wh[(2 * q + 1) * 128 + g * 32 + j];
    }

  f32x2 hr2[16];
#pragma unroll
  for (int q = 0; q < 16; ++q) { hr2[q][0] = 0.f; hr2[q][1] = 0.f; }
  float cj = 0.f, hj = 0.f;

  __shared__ __align__(16) float hs[2][32];

  const float* xp = xz + (size_t)b * (T_ * 128) + j;
  const float* mp = mask + (size_t)b * T_;

  // depth-4 prefetch ring (statically indexed via full unroll)
  float xgr[4][4];
  float mr[4];
#pragma unroll
  for (int s = 0; s < 4; ++s) {
#pragma unroll
    for (int g = 0; g < 4; ++g) xgr[s][g] = xp[s * 128 + g * 32];
    mr[s] = mp[s];
  }

  for (int t0 = 0; t0 < T_; t0 += 4) {
#pragma unroll
    for (int s = 0; s < 4; ++s) {
      const int t = t0 + s;
      // consume slot s
      f32x2 a[4];
#pragma unroll
      for (int g = 0; g < 4; ++g) { a[g][0] = xgr[s][g]; a[g][1] = 0.f; }
      const float m = mr[s];

      // refill slot s with step t+4 (clamped; tail loads are never consumed)
      int pf = t + 4;
      if (pf > T_ - 1) pf = T_ - 1;
#pragma unroll
      for (int g = 0; g < 4; ++g) xgr[s][g] = xp[(size_t)pf * 128 + g * 32];
      mr[s] = mp[pf];

      // recurrent matvec: 64 v_pk_fma_f32 (4 independent 16-deep chains)
#pragma unroll
      for (int q = 0; q < 16; ++q) {
#pragma unroll
        for (int g = 0; g < 4; ++g)
          asm("v_pk_fma_f32 %0, %1, %2, %0" : "+v"(a[g]) : "v"(hr2[q]), "v"(Whr[q][g]));
      }
      const float zi = a[0][0] + a[0][1];
      const float zf = a[1][0] + a[1][1];
      const float zg = a[2][0] + a[2][1];
      const float zo = a[3][0] + a[3][1];

      const float ig = sigmf(zi);
      const float fg = sigmf(zf);
      const float gg = tanhf_(zg);
      const float og = sigmf(zo);
      const float cn = fg * cj + ig * gg;
      const float hn = og * tanhf_(cn);
      cj += m * (cn - cj);          // masked: keep previous state where m==0
      hj += m * (hn - hj);

      hs[half][j] = hj;
      __syncthreads();
#pragma unroll
      for (int q = 0; q < 8; ++q) {
        const float4 v = *(const float4*)(&hs[half][q * 4]);
        hr2[2 * q][0]     = v.x; hr2[2 * q][1]     = v.y;
        hr2[2 * q + 1][0] = v.z; hr2[2 * q + 1][1] = v.w;
      }
    }
  }

  // FC + softmax (lane j==0 of each half writes)
  float hrs[32];
#pragma unroll
  for (int q = 0; q < 16; ++q) { hrs[2 * q] = hr2[q][0]; hrs[2 * q + 1] = hr2[q][1]; }
  float logits[C_];
#pragma unroll
  for (int c = 0; c < C_; ++c) {
    float aa = bfc[c];
#pragma unroll
    for (int f = 0; f < 32; ++f) aa += hrs[f] * Wfc[f * C_ + c];
    logits[c] = aa;
  }
  if (j == 0) {
    float mx = logits[0];
#pragma unroll
    for (int c = 1; c < C_; ++c) mx = fmaxf(mx, logits[c]);
    float e[C_], s = 0.f;
#pragma unroll
    for (int c = 0; c < C_; ++c) { e[c] = __expf(logits[c] - mx); s += e[c]; }
    const float rs = 1.f / s;
#pragma unroll
    for (int c = 0; c < C_; ++c) out[(size_t)b * C_ + c] = e[c] * rs;
  }
}

// ---------------------------------------------------------------------------
extern "C" void kernel_launch(void* const* d_in, const int* in_sizes, int n_in,
                              void* d_out, int out_size, void* d_ws, size_t ws_size,
                              hipStream_t stream) {
  const float* x   = (const float*)d_in[0];
  const float* Wx  = (const float*)d_in[1];
  const float* Wh  = (const float*)d_in[2];
  const float* bv  = (const float*)d_in[3];
  const float* Wfc = (const float*)d_in[4];
  const float* bfc = (const float*)d_in[5];
  float* out = (float*)d_out;

  float* xz   = (float*)d_ws;                                       // [B][T][128] f32 = 128 MB
  float* mask = (float*)((char*)d_ws + (size_t)B_ * T_ * 128 * 4);  // [B][T] f32 = 1 MB

  k_xz<<<(B_ * T_) / 128, 256, 0, stream>>>(x, Wx, bv, xz, mask);
  k_lstm<<<B_ / 2, 64, 0, stream>>>(xz, mask, Wh, Wfc, bfc, out);
}

// Round 7
// 268.442 us; speedup vs baseline: 1.1128x; 1.1128x over previous
//
#include <hip/hip_runtime.h>

#define B_ 512
#define T_ 512
#define F_ 128
#define H_ 32
#define C_ 6

typedef float f32x2 __attribute__((ext_vector_type(2)));

// ---------------------------------------------------------------------------
// Kernel 1: xz[row][c] = x[row,:] @ Wx[:,c] + bias[c],  row = b*T+t  (M=262144)
// Plain [b][t][128] output layout. mask[row] = any(x[row,:] != 0).
// 256 thr, tile 128x128, K in 2 chunks of 64, reg-prefetch double buffer,
// 64 KB LDS (2 blocks/CU), swizzled xl.  (~70-100 us, near f32 FMA floor.)
// ---------------------------------------------------------------------------
__global__ __launch_bounds__(256, 2) void k_xz(
    const float* __restrict__ x, const float* __restrict__ W,
    const float* __restrict__ bias, float* __restrict__ xz,
    float* __restrict__ mask)
{
  __shared__ float xl[128 * 64];   // 32 KB, XOR-swizzled rows
  __shared__ float wl[64 * 128];   // 32 KB, plain
  const int tid = threadIdx.x;
  const int m0  = blockIdx.x * 128;
  const int cg  = tid & 15;        // cols cg*4..+3 and 64+cg*4..+3
  const int rg  = tid >> 4;        // rows rg*8..+7

  float4 xpre[8], wpre[8];
  int rowbits = 0;

  auto load_chunk = [&](int ch) {
#pragma unroll
    for (int k = 0; k < 8; ++k) {
      const int u = tid + k * 256, r = u >> 4, q = u & 15;
      xpre[k] = *(const float4*)(x + (size_t)(m0 + r) * 128 + ch * 64 + q * 4);
    }
#pragma unroll
    for (int k = 0; k < 8; ++k) {
      const int u = tid + k * 256, f = u >> 5, q = u & 31;
      wpre[k] = *(const float4*)(W + (size_t)(ch * 64 + f) * 128 + q * 4);
    }
  };
  auto mask_chunk = [&]() {
#pragma unroll
    for (int k = 0; k < 8; ++k) {
      const float4 v = xpre[k];
      int nb = ((v.x != 0.f) || (v.y != 0.f) || (v.z != 0.f) || (v.w != 0.f)) ? 1 : 0;
      nb |= __shfl_xor(nb, 1); nb |= __shfl_xor(nb, 2);
      nb |= __shfl_xor(nb, 4); nb |= __shfl_xor(nb, 8);
      rowbits |= nb << k;
    }
  };
  auto write_chunk = [&]() {
#pragma unroll
    for (int k = 0; k < 8; ++k) {
      const int u = tid + k * 256, r = u >> 4, q = u & 15;
      *(float4*)(xl + r * 64 + ((q * 4) ^ (((r >> 3) & 3) << 2))) = xpre[k];
    }
#pragma unroll
    for (int k = 0; k < 8; ++k) {
      const int u = tid + k * 256, f = u >> 5, q = u & 31;
      *(float4*)(wl + f * 128 + q * 4) = wpre[k];
    }
  };

  float acc[8][8];
#pragma unroll
  for (int r = 0; r < 8; ++r)
#pragma unroll
    for (int u = 0; u < 8; ++u) acc[r][u] = 0.f;

  auto compute = [&]() {
#pragma unroll 2
    for (int fq = 0; fq < 16; ++fq) {
      float4 xv[8];
#pragma unroll
      for (int r = 0; r < 8; ++r)
        xv[r] = *(const float4*)(xl + (rg * 8 + r) * 64 + ((fq * 4) ^ ((rg & 3) << 2)));
#pragma unroll
      for (int ff = 0; ff < 4; ++ff) {
        const float* wr = wl + (fq * 4 + ff) * 128 + cg * 4;
        const float4 wa = *(const float4*)(wr);
        const float4 wb = *(const float4*)(wr + 64);
#pragma unroll
        for (int r = 0; r < 8; ++r) {
          const float xs = (ff == 0) ? xv[r].x : (ff == 1) ? xv[r].y
                         : (ff == 2) ? xv[r].z : xv[r].w;
          acc[r][0] += xs * wa.x;  acc[r][1] += xs * wa.y;
          acc[r][2] += xs * wa.z;  acc[r][3] += xs * wa.w;
          acc[r][4] += xs * wb.x;  acc[r][5] += xs * wb.y;
          acc[r][6] += xs * wb.z;  acc[r][7] += xs * wb.w;
        }
      }
    }
  };

  load_chunk(0);
  mask_chunk();
  write_chunk();
  __syncthreads();
  load_chunk(1);          // in flight during chunk-0 compute
  compute();
  __syncthreads();
  mask_chunk();
  write_chunk();
  __syncthreads();
  compute();

  // epilogue: bias + store (coalesced float4 pairs)
  float bb[8];
#pragma unroll
  for (int u = 0; u < 4; ++u) {
    bb[u]     = bias[cg * 4 + u];
    bb[4 + u] = bias[64 + cg * 4 + u];
  }
#pragma unroll
  for (int r = 0; r < 8; ++r) {
    float* op = xz + (size_t)(m0 + rg * 8 + r) * 128;
    float4 o0 = { acc[r][0] + bb[0], acc[r][1] + bb[1], acc[r][2] + bb[2], acc[r][3] + bb[3] };
    float4 o1 = { acc[r][4] + bb[4], acc[r][5] + bb[5], acc[r][6] + bb[6], acc[r][7] + bb[7] };
    *(float4*)(op + cg * 4)      = o0;
    *(float4*)(op + 64 + cg * 4) = o1;
  }
  if ((tid & 15) == 0) {
#pragma unroll
    for (int k = 0; k < 8; ++k)
      mask[m0 + k * 16 + rg] = (rowbits >> k) & 1 ? 1.f : 0.f;
  }
}

// ---------------------------------------------------------------------------
// Kernel 2: sequential LSTM scan + FC + softmax.  256 blocks x 64 threads.
// Wave = 2 batch rows; lane j owns gate col j of all 4 gates.
// KEY: no per-step __syncthreads (single-wave block; same-wave DS ops are
// processed in order, compiler inserts lgkmcnt for the RAW hazard). A
// barrier would force vmcnt(0) drain each step, putting full HBM/L3 load
// latency on the serial path (rounds 4/5: ~900 cyc/step). wave_barrier()
// is a pure scheduling fence - no waitcnt, prefetch loads stay in flight.
// Matvec in plain-C f32x2 (v_pk_fma_f32); NO inline asm -> operands may
// live in AGPRs (unified file, free) without forced v_accvgpr_read moves.
// ---------------------------------------------------------------------------
__device__ __forceinline__ float sigmf(float xx) {
  return __builtin_amdgcn_rcpf(1.f + __expf(-xx));
}
__device__ __forceinline__ float tanhf_(float xx) {
  return __builtin_amdgcn_rcpf(1.f + __expf(-2.f * xx)) * 2.f - 1.f;
}

__global__ __launch_bounds__(64, 1) void k_lstm(
    const float* __restrict__ xz, const float* __restrict__ mask,
    const float* __restrict__ Wh, const float* __restrict__ Wfc,
    const float* __restrict__ bfc, float* __restrict__ out)
{
  const int lane = threadIdx.x;
  const int half = lane >> 5;
  const int j = lane & 31;
  const int b = blockIdx.x * 2 + half;

  // Wh packed in f-pairs: Whr[q][g] = (Wh[2q][g*32+j], Wh[2q+1][g*32+j])
  f32x2 Whr[16][4];
#pragma unroll
  for (int q = 0; q < 16; ++q)
#pragma unroll
    for (int g = 0; g < 4; ++g) {
      Whr[q][g][0] = Wh[(2 * q)     * 128 + g * 32 + j];
      Whr[q][g][1] = Wh[(2 * q + 1) * 128 + g * 32 + j];
    }

  f32x2 hr2[16];
#pragma unroll
  for (int q = 0; q < 16; ++q) { hr2[q][0] = 0.f; hr2[q][1] = 0.f; }
  float cj = 0.f, hj = 0.f;

  __shared__ __align__(16) float hs[2][32];

  const float* xp = xz + (size_t)b * (T_ * 128) + j;
  const float* mp = mask + (size_t)b * T_;

  // depth-4 prefetch ring (statically indexed via full unroll)
  float xgr[4][4];
  float mr[4];
#pragma unroll
  for (int s = 0; s < 4; ++s) {
#pragma unroll
    for (int g = 0; g < 4; ++g) xgr[s][g] = xp[s * 128 + g * 32];
    mr[s] = mp[s];
  }

  for (int t0 = 0; t0 < T_; t0 += 4) {
#pragma unroll
    for (int s = 0; s < 4; ++s) {
      const int t = t0 + s;
      // consume slot s
      f32x2 a[4];
#pragma unroll
      for (int g = 0; g < 4; ++g) { a[g][0] = xgr[s][g]; a[g][1] = 0.f; }
      const float m = mr[s];

      // refill slot s with step t+4 (clamped; tail loads never consumed)
      int pf = t + 4;
      if (pf > T_ - 1) pf = T_ - 1;
#pragma unroll
      for (int g = 0; g < 4; ++g) xgr[s][g] = xp[(size_t)pf * 128 + g * 32];
      mr[s] = mp[pf];

      // recurrent matvec: 64 v_pk_fma_f32 (4 independent 16-deep chains)
#pragma unroll
      for (int q = 0; q < 16; ++q) {
#pragma unroll
        for (int g = 0; g < 4; ++g)
          a[g] += hr2[q] * Whr[q][g];
      }
      const float zi = a[0][0] + a[0][1];
      const float zf = a[1][0] + a[1][1];
      const float zg = a[2][0] + a[2][1];
      const float zo = a[3][0] + a[3][1];

      const float ig = sigmf(zi);
      const float fg = sigmf(zf);
      const float gg = tanhf_(zg);
      const float og = sigmf(zo);
      const float cn = fg * cj + ig * gg;
      const float hn = og * tanhf_(cn);
      cj += m * (cn - cj);          // masked: keep previous state where m==0
      hj += m * (hn - hj);

      hs[half][j] = hj;
      __builtin_amdgcn_wave_barrier();   // sched fence only: no vmcnt drain
#pragma unroll
      for (int q = 0; q < 8; ++q) {
        const float4 v = *(const float4*)(&hs[half][q * 4]);
        hr2[2 * q][0]     = v.x; hr2[2 * q][1]     = v.y;
        hr2[2 * q + 1][0] = v.z; hr2[2 * q + 1][1] = v.w;
      }
      __builtin_amdgcn_wave_barrier();   // keep next write after these reads
    }
  }

  // FC + softmax (lane j==0 of each half writes)
  float hrs[32];
#pragma unroll
  for (int q = 0; q < 16; ++q) { hrs[2 * q] = hr2[q][0]; hrs[2 * q + 1] = hr2[q][1]; }
  float logits[C_];
#pragma unroll
  for (int c = 0; c < C_; ++c) {
    float aa = bfc[c];
#pragma unroll
    for (int f = 0; f < 32; ++f) aa += hrs[f] * Wfc[f * C_ + c];
    logits[c] = aa;
  }
  if (j == 0) {
    float mx = logits[0];
#pragma unroll
    for (int c = 1; c < C_; ++c) mx = fmaxf(mx, logits[c]);
    float e[C_], s = 0.f;
#pragma unroll
    for (int c = 0; c < C_; ++c) { e[c] = __expf(logits[c] - mx); s += e[c]; }
    const float rs = 1.f / s;
#pragma unroll
    for (int c = 0; c < C_; ++c) out[(size_t)b * C_ + c] = e[c] * rs;
  }
}

// ---------------------------------------------------------------------------
extern "C" void kernel_launch(void* const* d_in, const int* in_sizes, int n_in,
                              void* d_out, int out_size, void* d_ws, size_t ws_size,
                              hipStream_t stream) {
  const float* x   = (const float*)d_in[0];
  const float* Wx  = (const float*)d_in[1];
  const float* Wh  = (const float*)d_in[2];
  const float* bv  = (const float*)d_in[3];
  const float* Wfc = (const float*)d_in[4];
  const float* bfc = (const float*)d_in[5];
  float* out = (float*)d_out;

  float* xz   = (float*)d_ws;                                       // [B][T][128] f32 = 128 MB
  float* mask = (float*)((char*)d_ws + (size_t)B_ * T_ * 128 * 4);  // [B][T] f32 = 1 MB

  k_xz<<<(B_ * T_) / 128, 256, 0, stream>>>(x, Wx, bv, xz, mask);
  k_lstm<<<B_ / 2, 64, 0, stream>>>(xz, mask, Wh, Wfc, bfc, out);
}